// Round 1
// baseline (70.646 us; speedup 1.0000x reference)
//
#include <hip/hip_runtime.h>

// AttentionConvFull: grouped 1x1 QKV + 5x5 per-channel local attention.
// B=4, H=W=56, C=OC=256, G=8, Cg=32, K=5, pad=2.
// One block = one (batch, 8x8 spatial tile, group). 256 threads:
//   c = tid & 31 (channel within group), p0 = tid >> 5 (pixel slice).

constexpr int TB = 4, TH = 56, TW = 56, TC = 256;
constexpr int G  = 8, CG = 32, KK = 5, PAD = 2;
constexpr int TILE = 8;
constexpr int HT = TILE + 2 * PAD;   // 12 (halo tile edge)
constexpr int NT = TH / TILE;        // 7 tiles per dim
constexpr int NPIX_HALO = HT * HT;   // 144

__global__ __launch_bounds__(256, 2)
void attn_conv_full_kernel(const float* __restrict__ x,
                           const float* __restrict__ wq,
                           const float* __restrict__ wk,
                           const float* __restrict__ wv,
                           const float* __restrict__ rel,
                           const float* __restrict__ qemb,
                           float* __restrict__ out) {
    __shared__ float xs[NPIX_HALO][CG];   // 18 KB
    __shared__ float ks[NPIX_HALO][CG];   // 18 KB
    __shared__ float vs[NPIX_HALO][CG];   // 18 KB
    __shared__ float rels[CG][25];        // 3.2 KB (stride 25: conflict-free)

    const int bid  = blockIdx.x;
    const int g    = bid & 7;
    const int tile = bid >> 3;
    const int tj   = tile % NT;
    const int ti   = (tile / NT) % NT;
    const int b    = tile / (NT * NT);

    const int t  = threadIdx.x;
    const int c  = t & 31;
    const int p0 = t >> 5;   // 0..7

    // stage this group's rel_emb rows: rel layout (G, Cg, K, K)
    for (int i = t; i < CG * 25; i += 256) {
        rels[i / 25][i % 25] = rel[g * CG * 25 + i];
    }

    // ---- phase 1: load x halo tile (zero OOB; pad-then-conv == conv-then-pad for 1x1)
    const int h0 = ti * TILE - PAD, w0 = tj * TILE - PAD;
    for (int it = 0; it < NPIX_HALO / 8; ++it) {
        const int hp = p0 + it * 8;
        const int hi = hp / HT, hj = hp % HT;
        const int gh = h0 + hi, gw = w0 + hj;
        float val = 0.f;
        if (gh >= 0 && gh < TH && gw >= 0 && gw < TW)
            val = x[(((size_t)b * TH + gh) * TW + gw) * TC + g * CG + c];
        xs[hp][c] = val;
    }

    // weight rows for this thread's output channel (held in registers)
    float wqr[CG], wkr[CG], wvr[CG];
    {
        const float* wqp = wq + (size_t)(g * CG + c) * CG;
        const float* wkp = wk + (size_t)(g * CG + c) * CG;
        const float* wvp = wv + (size_t)(g * CG + c) * CG;
#pragma unroll
        for (int i = 0; i < CG; ++i) { wqr[i] = wqp[i]; wkr[i] = wkp[i]; wvr[i] = wvp[i]; }
    }
    const float qe = qemb[g * CG + c];

    __syncthreads();

    // ---- phase 2: k,v for all 144 halo pixels; q (+q_emb) for 64 interior pixels
    for (int it = 0; it < NPIX_HALO / 8; ++it) {
        const int hp = p0 + it * 8;
        const float4* xp = (const float4*)&xs[hp][0];
        float acck = 0.f, accv = 0.f;
#pragma unroll
        for (int i4 = 0; i4 < CG / 4; ++i4) {
            const float4 xv = xp[i4];
            acck += wkr[4*i4+0]*xv.x; accv += wvr[4*i4+0]*xv.x;
            acck += wkr[4*i4+1]*xv.y; accv += wvr[4*i4+1]*xv.y;
            acck += wkr[4*i4+2]*xv.z; accv += wvr[4*i4+2]*xv.z;
            acck += wkr[4*i4+3]*xv.w; accv += wvr[4*i4+3]*xv.w;
        }
        ks[hp][c] = acck;
        vs[hp][c] = accv;
    }

    float qreg[8];
#pragma unroll
    for (int it = 0; it < 8; ++it) {
        // interior pixel: row ii = it, col ij = p0
        const int hp = (it + PAD) * HT + (p0 + PAD);
        const float4* xp = (const float4*)&xs[hp][0];
        float acc = qe;
#pragma unroll
        for (int i4 = 0; i4 < CG / 4; ++i4) {
            const float4 xv = xp[i4];
            acc += wqr[4*i4+0]*xv.x + wqr[4*i4+1]*xv.y
                 + wqr[4*i4+2]*xv.z + wqr[4*i4+3]*xv.w;
        }
        qreg[it] = acc;
    }

    __syncthreads();

    // hoist this channel's rel row into registers
    float relr[25];
#pragma unroll
    for (int i = 0; i < 25; ++i) relr[i] = rels[c][i];

    // ---- phase 3: per-channel softmax attention over the 5x5 window
#pragma unroll
    for (int it = 0; it < 8; ++it) {
        const int ii = it, ij = p0;
        const float qv = qreg[it];
        float l[25];
        float m = -1e30f;
#pragma unroll
        for (int di = 0; di < KK; ++di) {
#pragma unroll
            for (int dj = 0; dj < KK; ++dj) {
                const int idx = di * KK + dj;
                const int hp  = (ii + di) * HT + (ij + dj);
                const float kv = ks[hp][c] + relr[idx];
                const float lg = qv * kv;
                l[idx] = lg;
                m = fmaxf(m, lg);
            }
        }
        float s = 0.f, acc = 0.f;
#pragma unroll
        for (int di = 0; di < KK; ++di) {
#pragma unroll
            for (int dj = 0; dj < KK; ++dj) {
                const int idx = di * KK + dj;
                const int hp  = (ii + di) * HT + (ij + dj);
                const float e = __expf(l[idx] - m);
                s   += e;
                acc += e * vs[hp][c];
            }
        }
        const int gh = ti * TILE + ii, gw = tj * TILE + ij;
        out[(((size_t)b * TH + gh) * TW + gw) * TC + g * CG + c] = acc / s;
    }
}

extern "C" void kernel_launch(void* const* d_in, const int* in_sizes, int n_in,
                              void* d_out, int out_size, void* d_ws, size_t ws_size,
                              hipStream_t stream) {
    const float* x    = (const float*)d_in[0];
    const float* wq   = (const float*)d_in[1];
    const float* wk   = (const float*)d_in[2];
    const float* wv   = (const float*)d_in[3];
    const float* rel  = (const float*)d_in[4];
    const float* qemb = (const float*)d_in[5];
    float* out = (float*)d_out;

    const int nblocks = TB * NT * NT * G;   // 4*7*7*8 = 1568
    hipLaunchKernelGGL(attn_conv_full_kernel, dim3(nblocks), dim3(256), 0, stream,
                       x, wq, wk, wv, rel, qemb, out);
}

// Round 2
// 68.373 us; speedup vs baseline: 1.0332x; 1.0332x over previous
//
#include <hip/hip_runtime.h>

// AttentionConvFull: grouped 1x1 QKV + 5x5 per-channel local attention.
// B=4, H=W=56, C=OC=256, G=8, Cg=32, K=5, pad=2.
//
// Two-kernel plan:
//   K1 (qkv):  q/k/v = grouped 1x1 conv of x (+q_emb on q), written to d_ws.
//   K2 (attn): per (batch, 8x8 tile, group): stage k,v halo (12x12x32) in LDS,
//              sliding 5x5 register window, fused single-pass softmax (no max-sub,
//              exp2 with q pre-scaled by log2e).
// Fallback: if ws_size too small, use the round-1 fused kernel.

constexpr int TB = 4, TH = 56, TW = 56, TC = 256;
constexpr int G  = 8, CG = 32, KK = 5, PAD = 2;
constexpr int TILE = 8;
constexpr int HT = TILE + 2 * PAD;   // 12
constexpr int NT = TH / TILE;        // 7
constexpr int NPIX_HALO = HT * HT;   // 144
constexpr float LOG2E = 1.44269504088896340736f;

// ---------------- Kernel 1: QKV projection ----------------
constexpr int PPB = 16;   // pixels per block

__global__ __launch_bounds__(256, 2)
void qkv_kernel(const float* __restrict__ x,
                const float* __restrict__ wq,
                const float* __restrict__ wk,
                const float* __restrict__ wv,
                const float* __restrict__ qemb,
                float* __restrict__ qm, float* __restrict__ km, float* __restrict__ vm) {
    __shared__ float xs[PPB][TC];   // 16 KB
    const int t = threadIdx.x;
    const size_t base = (size_t)blockIdx.x * PPB * TC;

    // coalesced float4 load of the 16-pixel strip (16*256 floats)
    {
        const float4* xg = (const float4*)(x + base);
        float4* xsv = (float4*)&xs[0][0];
#pragma unroll
        for (int i = 0; i < PPB * TC / 4 / 256; ++i)   // 4 iters
            xsv[t + i * 256] = xg[t + i * 256];
    }

    const int c = t;            // output channel 0..255
    const int g = c >> 5;
    float wqr[CG], wkr[CG], wvr[CG];
    {
        const float4* wqp = (const float4*)(wq + (size_t)c * CG);
        const float4* wkp = (const float4*)(wk + (size_t)c * CG);
        const float4* wvp = (const float4*)(wv + (size_t)c * CG);
#pragma unroll
        for (int i = 0; i < CG / 4; ++i) {
            float4 a = wqp[i], bb = wkp[i], cc = wvp[i];
            wqr[4*i+0]=a.x; wqr[4*i+1]=a.y; wqr[4*i+2]=a.z; wqr[4*i+3]=a.w;
            wkr[4*i+0]=bb.x; wkr[4*i+1]=bb.y; wkr[4*i+2]=bb.z; wkr[4*i+3]=bb.w;
            wvr[4*i+0]=cc.x; wvr[4*i+1]=cc.y; wvr[4*i+2]=cc.z; wvr[4*i+3]=cc.w;
        }
    }
    const float qe = qemb[c];
    __syncthreads();

    for (int p = 0; p < PPB; ++p) {
        const float4* xp = (const float4*)&xs[p][g * CG];   // broadcast within group
        float aq = qe, ak = 0.f, av = 0.f;
#pragma unroll
        for (int i = 0; i < CG / 4; ++i) {
            const float4 xv = xp[i];
            aq += wqr[4*i+0]*xv.x + wqr[4*i+1]*xv.y + wqr[4*i+2]*xv.z + wqr[4*i+3]*xv.w;
            ak += wkr[4*i+0]*xv.x + wkr[4*i+1]*xv.y + wkr[4*i+2]*xv.z + wkr[4*i+3]*xv.w;
            av += wvr[4*i+0]*xv.x + wvr[4*i+1]*xv.y + wvr[4*i+2]*xv.z + wvr[4*i+3]*xv.w;
        }
        qm[base + p * TC + c] = aq;
        km[base + p * TC + c] = ak;
        vm[base + p * TC + c] = av;
    }
}

// ---------------- Kernel 2: local attention ----------------
__global__ __launch_bounds__(256, 4)
void attn_kernel(const float* __restrict__ qm,
                 const float* __restrict__ km,
                 const float* __restrict__ vm,
                 const float* __restrict__ rel,
                 float* __restrict__ out) {
    __shared__ float ks[NPIX_HALO][CG];   // 18 KB
    __shared__ float vs[NPIX_HALO][CG];   // 18 KB
    __shared__ float rels[CG][25];        // 3.2 KB

    const int bid  = blockIdx.x;
    const int g    = bid & 7;
    const int tile = bid >> 3;
    const int tj   = tile % NT;
    const int ti   = (tile / NT) % NT;
    const int b    = tile / (NT * NT);

    const int t  = threadIdx.x;
    const int c  = t & 31;
    const int p0 = t >> 5;

    // rel rows for this group
    for (int i = t; i < CG * 25; i += 256)
        rels[i / 25][i % 25] = rel[g * CG * 25 + i];

    // stage k,v halo with float4: 8 lanes cover one pixel's 32 channels
    const int c4 = t & 7, pp = t >> 3;   // pp: 0..31
    const int h0 = ti * TILE - PAD, w0 = tj * TILE - PAD;
#pragma unroll
    for (int it = 0; it < 5; ++it) {
        const int hp = pp + it * 32;
        if (hp < NPIX_HALO) {
            const int hi = hp / HT, hj = hp % HT;
            const int gh = h0 + hi, gw = w0 + hj;
            float4 kv = make_float4(0.f, 0.f, 0.f, 0.f);
            float4 vv = kv;
            if (gh >= 0 && gh < TH && gw >= 0 && gw < TW) {
                const size_t off = (((size_t)b * TH + gh) * TW + gw) * TC + g * CG + c4 * 4;
                kv = *(const float4*)(km + off);
                vv = *(const float4*)(vm + off);
            }
            *(float4*)&ks[hp][c4 * 4] = kv;
            *(float4*)&vs[hp][c4 * 4] = vv;
        }
    }

    // q for this thread's 8 interior pixels (column p0), pre-scaled by log2e
    float qreg[8];
#pragma unroll
    for (int ii = 0; ii < 8; ++ii) {
        const int gh = ti * TILE + ii, gw = tj * TILE + p0;
        qreg[ii] = qm[(((size_t)b * TH + gh) * TW + gw) * TC + g * CG + c] * LOG2E;
    }

    __syncthreads();

    float relr[25];
#pragma unroll
    for (int i = 0; i < 25; ++i) relr[i] = rels[c][i];

    // sliding 5x5 register window over halo rows (slot = halo_row % 5)
    float kw[5][5], vw[5][5];
#pragma unroll
    for (int r = 0; r < 5; ++r)
#pragma unroll
        for (int j = 0; j < 5; ++j) {
            kw[r][j] = ks[r * HT + p0 + j][c];
            vw[r][j] = vs[r * HT + p0 + j][c];
        }

#pragma unroll
    for (int ii = 0; ii < 8; ++ii) {
        const float qv2 = qreg[ii];
        float s = 0.f, acc = 0.f;
#pragma unroll
        for (int di = 0; di < 5; ++di) {
            const int r = (ii + di) % 5;     // compile-time after unroll
#pragma unroll
            for (int dj = 0; dj < 5; ++dj) {
                const float e = exp2f(qv2 * (kw[r][dj] + relr[di * 5 + dj]));
                s += e;
                acc = fmaf(e, vw[r][dj], acc);
            }
        }
        const int gh = ti * TILE + ii, gw = tj * TILE + p0;
        out[(((size_t)b * TH + gh) * TW + gw) * TC + g * CG + c] = acc / s;

        if (ii < 7) {
            const int r = ii % 5;            // evicted slot <- halo row ii+5
            const int hrow = ii + 5;
#pragma unroll
            for (int j = 0; j < 5; ++j) {
                kw[r][j] = ks[hrow * HT + p0 + j][c];
                vw[r][j] = vs[hrow * HT + p0 + j][c];
            }
        }
    }
}

// ---------------- Fallback: round-1 fused kernel ----------------
__global__ __launch_bounds__(256, 2)
void attn_conv_full_kernel(const float* __restrict__ x,
                           const float* __restrict__ wq,
                           const float* __restrict__ wk,
                           const float* __restrict__ wv,
                           const float* __restrict__ rel,
                           const float* __restrict__ qemb,
                           float* __restrict__ out) {
    __shared__ float xs[NPIX_HALO][CG];
    __shared__ float ks[NPIX_HALO][CG];
    __shared__ float vs[NPIX_HALO][CG];
    __shared__ float rels[CG][25];

    const int bid  = blockIdx.x;
    const int g    = bid & 7;
    const int tile = bid >> 3;
    const int tj   = tile % NT;
    const int ti   = (tile / NT) % NT;
    const int b    = tile / (NT * NT);

    const int t  = threadIdx.x;
    const int c  = t & 31;
    const int p0 = t >> 5;

    for (int i = t; i < CG * 25; i += 256)
        rels[i / 25][i % 25] = rel[g * CG * 25 + i];

    const int h0 = ti * TILE - PAD, w0 = tj * TILE - PAD;
    for (int it = 0; it < NPIX_HALO / 8; ++it) {
        const int hp = p0 + it * 8;
        const int hi = hp / HT, hj = hp % HT;
        const int gh = h0 + hi, gw = w0 + hj;
        float val = 0.f;
        if (gh >= 0 && gh < TH && gw >= 0 && gw < TW)
            val = x[(((size_t)b * TH + gh) * TW + gw) * TC + g * CG + c];
        xs[hp][c] = val;
    }

    float wqr[CG], wkr[CG], wvr[CG];
    {
        const float* wqp = wq + (size_t)(g * CG + c) * CG;
        const float* wkp = wk + (size_t)(g * CG + c) * CG;
        const float* wvp = wv + (size_t)(g * CG + c) * CG;
#pragma unroll
        for (int i = 0; i < CG; ++i) { wqr[i] = wqp[i]; wkr[i] = wkp[i]; wvr[i] = wvp[i]; }
    }
    const float qe = qemb[g * CG + c];
    __syncthreads();

    for (int it = 0; it < NPIX_HALO / 8; ++it) {
        const int hp = p0 + it * 8;
        const float4* xp = (const float4*)&xs[hp][0];
        float acck = 0.f, accv = 0.f;
#pragma unroll
        for (int i4 = 0; i4 < CG / 4; ++i4) {
            const float4 xv = xp[i4];
            acck += wkr[4*i4+0]*xv.x; accv += wvr[4*i4+0]*xv.x;
            acck += wkr[4*i4+1]*xv.y; accv += wvr[4*i4+1]*xv.y;
            acck += wkr[4*i4+2]*xv.z; accv += wvr[4*i4+2]*xv.z;
            acck += wkr[4*i4+3]*xv.w; accv += wvr[4*i4+3]*xv.w;
        }
        ks[hp][c] = acck;
        vs[hp][c] = accv;
    }

    float qreg[8];
#pragma unroll
    for (int it = 0; it < 8; ++it) {
        const int hp = (it + PAD) * HT + (p0 + PAD);
        const float4* xp = (const float4*)&xs[hp][0];
        float acc = qe;
#pragma unroll
        for (int i4 = 0; i4 < CG / 4; ++i4) {
            const float4 xv = xp[i4];
            acc += wqr[4*i4+0]*xv.x + wqr[4*i4+1]*xv.y
                 + wqr[4*i4+2]*xv.z + wqr[4*i4+3]*xv.w;
        }
        qreg[it] = acc;
    }
    __syncthreads();

    float relr[25];
#pragma unroll
    for (int i = 0; i < 25; ++i) relr[i] = rels[c][i];

#pragma unroll
    for (int it = 0; it < 8; ++it) {
        const int ii = it, ij = p0;
        const float qv = qreg[it];
        float l[25];
        float m = -1e30f;
#pragma unroll
        for (int di = 0; di < KK; ++di)
#pragma unroll
            for (int dj = 0; dj < KK; ++dj) {
                const int idx = di * KK + dj;
                const int hp  = (ii + di) * HT + (ij + dj);
                const float kv = ks[hp][c] + relr[idx];
                const float lg = qv * kv;
                l[idx] = lg;
                m = fmaxf(m, lg);
            }
        float s = 0.f, acc = 0.f;
#pragma unroll
        for (int di = 0; di < KK; ++di)
#pragma unroll
            for (int dj = 0; dj < KK; ++dj) {
                const int idx = di * KK + dj;
                const int hp  = (ii + di) * HT + (ij + dj);
                const float e = __expf(l[idx] - m);
                s   += e;
                acc += e * vs[hp][c];
            }
        const int gh = ti * TILE + ii, gw = tj * TILE + ij;
        out[(((size_t)b * TH + gh) * TW + gw) * TC + g * CG + c] = acc / s;
    }
}

extern "C" void kernel_launch(void* const* d_in, const int* in_sizes, int n_in,
                              void* d_out, int out_size, void* d_ws, size_t ws_size,
                              hipStream_t stream) {
    const float* x    = (const float*)d_in[0];
    const float* wq   = (const float*)d_in[1];
    const float* wk   = (const float*)d_in[2];
    const float* wv   = (const float*)d_in[3];
    const float* rel  = (const float*)d_in[4];
    const float* qemb = (const float*)d_in[5];
    float* out = (float*)d_out;

    const size_t npix_tot = (size_t)TB * TH * TW;           // 12544
    const size_t map_elems = npix_tot * TC;                 // 3,211,264
    const size_t need = 3 * map_elems * sizeof(float);      // ~38.6 MB

    if (ws_size >= need) {
        float* qmap = (float*)d_ws;
        float* kmap = qmap + map_elems;
        float* vmap = kmap + map_elems;
        hipLaunchKernelGGL(qkv_kernel, dim3(npix_tot / PPB), dim3(256), 0, stream,
                           x, wq, wk, wv, qemb, qmap, kmap, vmap);
        hipLaunchKernelGGL(attn_kernel, dim3(TB * NT * NT * G), dim3(256), 0, stream,
                           qmap, kmap, vmap, rel, out);
    } else {
        hipLaunchKernelGGL(attn_conv_full_kernel, dim3(TB * NT * NT * G), dim3(256), 0, stream,
                           x, wq, wk, wv, rel, qemb, out);
    }
}